// Round 4
// baseline (112.135 us; speedup 1.0000x reference)
//
#include <hip/hip_runtime.h>
#include <stdint.h>
#include <math.h>

#define B_DIM 4096
#define H_DIM 1024
#define NI_DIM 4096
#define NQ_DIM 2048
#define K_DIM 5120   // H + NI
#define NKT 160      // K_DIM / 32

typedef __attribute__((ext_vector_type(8))) short short8;
typedef __attribute__((ext_vector_type(4))) float f32x4;

__device__ __forceinline__ unsigned short f2bf(float f) {
  unsigned u = __float_as_uint(f);
  u += 0x7FFFu + ((u >> 16) & 1u);  // round-to-nearest-even
  return (unsigned short)(u >> 16);
}

__device__ __forceinline__ void gload_lds16(const void* g, void* l) {
  __builtin_amdgcn_global_load_lds(
      (__attribute__((address_space(1))) void*)(uintptr_t)g,
      (__attribute__((address_space(3))) void*)l, 16, 0, 0);
}

// fp32 -> bf16 cast into staged-tile layout:
//   dst chunk16 index = ((rowTile*NKT + kt)*4 + slot)*128 + row_in_tile
// GEMM staging reads are contiguous 16B chunks AND the implied LDS layout
// [slot][row][8] makes ds_read_b128 the canonical conflict-free pattern
// (verified: SQ_LDS_BANK_CONFLICT == 0).
__global__ __launch_bounds__(256) void cast_tile(
    const float* __restrict__ src0, const float* __restrict__ src1,
    short* __restrict__ dst) {
  __shared__ __align__(16) short lds[4096];  // [4][128][8]
  const unsigned bt = blockIdx.x;
  const int rowTile = bt / NKT;
  const int kt = bt % NKT;
  const float* src;
  long long srcBase;
  int cols;
  if (kt < 32) { src = src0; cols = 1024; srcBase = (long long)kt * 32; }
  else         { src = src1; cols = 4096; srcBase = (long long)(kt - 32) * 32; }
  const int tid = threadIdx.x;
#pragma unroll
  for (int half = 0; half < 2; ++half) {
    int c = tid + half * 256;          // cell: row r = c>>2, slot s = c&3
    int r = c >> 2, s = c & 3;
    long long sa = ((long long)(rowTile * 128 + r)) * cols + srcBase + s * 8;
    float4 v0 = *(const float4*)(src + sa);
    float4 v1 = *(const float4*)(src + sa + 4);
    short8 o;
    o[0] = (short)f2bf(v0.x); o[1] = (short)f2bf(v0.y);
    o[2] = (short)f2bf(v0.z); o[3] = (short)f2bf(v0.w);
    o[4] = (short)f2bf(v1.x); o[5] = (short)f2bf(v1.y);
    o[6] = (short)f2bf(v1.z); o[7] = (short)f2bf(v1.w);
    *(short8*)(&lds[(s * 128 + r) * 8]) = o;
  }
  __syncthreads();
  short* dtile = dst + (((long long)rowTile * NKT + kt) * 512) * 8;
#pragma unroll
  for (int half = 0; half < 2; ++half) {
    int c = tid + half * 256;
    *(short8*)(dtile + c * 8) = *(const short8*)(&lds[c * 8]);
  }
}

// Split-K GEMM, software-pipelined: A triple-buffered (2-iter latency slack,
// covers HBM ~900cy), B double-buffered (1-iter slack, B panels are
// L2-resident: 2.6MB/XCD). Raw s_barrier + counted vmcnt(4) -- never drains
// to 0 in steady state. Issue order per iter: B(t+1) then A(t+2), so FIFO
// invariant: after iter-t's wait, only A(t+1)'s 4 loads remain in flight.
// LDS = 3*8 + 2*8 = 40KB -> 4 blocks/CU.
__global__ __launch_bounds__(256, 4) void gemm_splitk(
    const short* __restrict__ Xc, const short* __restrict__ Wc,
    float* __restrict__ P, int ntk) {
  __shared__ __align__(16) short As[3][4096];
  __shared__ __align__(16) short Bs[2][4096];
  const int tid = threadIdx.x;
  const int lane = tid & 63;
  const int wid = tid >> 6;
  const int wm = wid >> 1, wn = wid & 1;
  const int fr = lane & 15, fq = lane >> 4;

  const int nwg = gridDim.x;
  const int orig = blockIdx.x;
  const int cpx = nwg >> 3;
  const int swz = (orig & 7) * cpx + (orig >> 3);
  const int bz = swz >> 8;
  const int bm = (swz >> 3) & 31;
  const int bn = swz & 7;
  const int kt0 = bz * ntk;

  const int c0 = tid, c1 = tid + 256;
  const short* gA = Xc + (((long long)bm * NKT + kt0) << 12);  // *4096 shorts
  const short* gB = Wc + (((long long)bn * NKT + kt0) << 12);

  f32x4 acc[4][4] = {};

  // prologue: A(0), B(0), A(1)  (FIFO order matters)
  gload_lds16(gA + c0 * 8, &As[0][c0 * 8]);
  gload_lds16(gA + c1 * 8, &As[0][c1 * 8]);
  gload_lds16(gB + c0 * 8, &Bs[0][c0 * 8]);
  gload_lds16(gB + c1 * 8, &Bs[0][c1 * 8]);
  gload_lds16(gA + 4096 + c0 * 8, &As[1][c0 * 8]);
  gload_lds16(gA + 4096 + c1 * 8, &As[1][c1 * 8]);

  for (int t = 0; t < ntk; ++t) {
    // wait: everything except A(t+1) landed (A(t): 2-iter-old, B(t): 1-iter-old)
    if (t + 1 < ntk) {
      asm volatile("s_waitcnt vmcnt(4)" ::: "memory");
    } else {
      asm volatile("s_waitcnt vmcnt(0)" ::: "memory");
    }
    asm volatile("s_barrier" ::: "memory");

    if (t + 1 < ntk) {  // B(t+1) -> Bs[(t+1)&1]
      const short* nB = gB + (long long)(t + 1) * 4096;
      short* lB = &Bs[(t + 1) & 1][0];
      gload_lds16(nB + c0 * 8, lB + c0 * 8);
      gload_lds16(nB + c1 * 8, lB + c1 * 8);
    }
    if (t + 2 < ntk) {  // A(t+2) -> As[(t+2)%3]
      const short* nA = gA + (long long)(t + 2) * 4096;
      short* lA = &As[(t + 2) % 3][0];
      gload_lds16(nA + c0 * 8, lA + c0 * 8);
      gload_lds16(nA + c1 * 8, lA + c1 * 8);
    }

    const short* a_base = &As[t % 3][0];
    const short* b_base = &Bs[t & 1][0];
    short8 av[4], bv[4];
#pragma unroll
    for (int i = 0; i < 4; i++) {
      // [slot=fq][row = w*64 + i*16 + fr][8] -> conflict-free granules
      av[i] = *(const short8*)(a_base + (fq * 128 + wm * 64 + i * 16 + fr) * 8);
      bv[i] = *(const short8*)(b_base + (fq * 128 + wn * 64 + i * 16 + fr) * 8);
    }
#pragma unroll
    for (int mi = 0; mi < 4; mi++)
#pragma unroll
      for (int ni = 0; ni < 4; ni++)
        acc[mi][ni] = __builtin_amdgcn_mfma_f32_16x16x32_bf16(
            av[mi], bv[ni], acc[mi][ni], 0, 0, 0);
  }

  // write fp32 partial; C/D layout col=lane&15, row=(lane>>4)*4+reg
  float* Pp = P + (long long)bz * B_DIM * H_DIM;
  const int row0 = bm * 128 + wm * 64;
  const int col0 = bn * 128 + wn * 64;
#pragma unroll
  for (int ni = 0; ni < 4; ni++) {
    int col = col0 + ni * 16 + fr;
#pragma unroll
    for (int mi = 0; mi < 4; mi++) {
#pragma unroll
      for (int r = 0; r < 4; r++) {
        int row = row0 + mi * 16 + fq * 4 + r;
        Pp[(long long)row * H_DIM + col] = acc[mi][ni][r];
      }
    }
  }
}

// hidden = tanh(sum_z P[z] + b_t + b_x); hidden base is NOT 16B-aligned
// (d_out + 4097 floats) -> scalar stores.
__global__ __launch_bounds__(256) void reduce_bias_tanh(
    const float* __restrict__ P, const float* __restrict__ bt,
    const float* __restrict__ bx, float* __restrict__ hidden, int S) {
  const long long total4 = (long long)B_DIM * H_DIM / 4;
  for (long long e = (long long)blockIdx.x * 256 + threadIdx.x; e < total4;
       e += (long long)gridDim.x * 256) {
    long long base = e * 4;
    int col = (int)(base & (H_DIM - 1));
    float4 s = *(const float4*)(P + base);
    for (int z = 1; z < S; ++z) {
      float4 p = *(const float4*)(P + (long long)z * B_DIM * H_DIM + base);
      s.x += p.x; s.y += p.y; s.z += p.z; s.w += p.w;
    }
    float4 bt4 = *(const float4*)(bt + col);
    float4 bx4 = *(const float4*)(bx + col);
    hidden[base + 0] = tanhf(s.x + bt4.x + bx4.x);
    hidden[base + 1] = tanhf(s.y + bt4.y + bx4.y);
    hidden[base + 2] = tanhf(s.z + bt4.z + bx4.z);
    hidden[base + 3] = tanhf(s.w + bt4.w + bx4.w);
  }
}

// One block per batch row: find one-hot index(es) in inputY (float4 scan),
// dot hidden row with selected W_y row(s), sigmoid, pred + BCE term.
__global__ __launch_bounds__(256) void pred_err(
    const float* __restrict__ hidden, const float* __restrict__ Y,
    const float* __restrict__ truth, const float* __restrict__ Wy,
    const float* __restrict__ by, float* __restrict__ predOut,
    float* __restrict__ bce) {
  const int b = blockIdx.x;
  const int tid = threadIdx.x;
  __shared__ int s_cnt;
  __shared__ int s_idx[8];
  __shared__ float s_val[8];
  __shared__ float s_red[4];
  if (tid == 0) s_cnt = 0;
  __syncthreads();
  const float4* Yr = (const float4*)(Y + (long long)b * NQ_DIM);
#pragma unroll
  for (int h = 0; h < NQ_DIM / 4 / 256; ++h) {
    int j = tid + h * 256;
    float4 v = Yr[j];
    if (v.x != 0.0f) { int p = atomicAdd(&s_cnt, 1); if (p < 8) { s_idx[p] = 4 * j;     s_val[p] = v.x; } }
    if (v.y != 0.0f) { int p = atomicAdd(&s_cnt, 1); if (p < 8) { s_idx[p] = 4 * j + 1; s_val[p] = v.y; } }
    if (v.z != 0.0f) { int p = atomicAdd(&s_cnt, 1); if (p < 8) { s_idx[p] = 4 * j + 2; s_val[p] = v.z; } }
    if (v.w != 0.0f) { int p = atomicAdd(&s_cnt, 1); if (p < 8) { s_idx[p] = 4 * j + 3; s_val[p] = v.w; } }
  }
  __syncthreads();
  int cnt = s_cnt < 8 ? s_cnt : 8;
  const float* Hr = hidden + (long long)b * H_DIM;
  float h0 = Hr[tid * 4 + 0], h1 = Hr[tid * 4 + 1];
  float h2 = Hr[tid * 4 + 2], h3 = Hr[tid * 4 + 3];
  float predv = 0.0f;
  for (int it = 0; it < cnt; ++it) {
    int q = s_idx[it];
    float4 w = *(const float4*)(Wy + (long long)q * H_DIM + tid * 4);
    float part = h0 * w.x + h1 * w.y + h2 * w.z + h3 * w.w;
#pragma unroll
    for (int off = 32; off > 0; off >>= 1) part += __shfl_down(part, off, 64);
    if ((tid & 63) == 0) s_red[tid >> 6] = part;
    __syncthreads();
    if (tid == 0) {
      float z = s_red[0] + s_red[1] + s_red[2] + s_red[3] + by[q];
      float p = 1.0f / (1.0f + expf(-z));
      predv += s_val[it] * p;
    }
    __syncthreads();
  }
  if (tid == 0) {
    predOut[b] = predv;
    float t = truth[b];
    float lp = fmaxf(logf(predv), -100.0f);
    float l1p = fmaxf(log1pf(-predv), -100.0f);
    bce[b] = -(t * lp + (1.0f - t) * l1p);
  }
}

__global__ __launch_bounds__(256) void reduce_err(
    const float* __restrict__ bce, float* __restrict__ errOut) {
  float s = 0.0f;
  for (int i = threadIdx.x; i < B_DIM; i += 256) s += bce[i];
#pragma unroll
  for (int off = 32; off > 0; off >>= 1) s += __shfl_down(s, off, 64);
  __shared__ float red[4];
  if ((threadIdx.x & 63) == 0) red[threadIdx.x >> 6] = s;
  __syncthreads();
  if (threadIdx.x == 0) errOut[0] = red[0] + red[1] + red[2] + red[3];
}

extern "C" void kernel_launch(void* const* d_in, const int* in_sizes, int n_in,
                              void* d_out, int out_size, void* d_ws, size_t ws_size,
                              hipStream_t stream) {
  (void)in_sizes; (void)n_in; (void)out_size;
  const float* state  = (const float*)d_in[0];
  const float* inputX = (const float*)d_in[1];
  const float* inputY = (const float*)d_in[2];
  const float* truth  = (const float*)d_in[3];
  const float* W_t    = (const float*)d_in[4];
  const float* b_t    = (const float*)d_in[5];
  const float* W_x    = (const float*)d_in[6];
  const float* b_x    = (const float*)d_in[7];
  const float* W_y    = (const float*)d_in[8];
  const float* b_y    = (const float*)d_in[9];

  const size_t XC_B = (size_t)B_DIM * K_DIM * 2;   // 41.9 MB
  const size_t WC_B = (size_t)H_DIM * K_DIM * 2;   // 10.5 MB
  const size_t PART = (size_t)B_DIM * H_DIM * 4;   // 16.8 MB per split

  int S = 1;
  if (ws_size >= XC_B + WC_B + 4 * PART + 16384) S = 4;
  else if (ws_size >= XC_B + WC_B + 2 * PART + 16384) S = 2;

  short* Xc = (short*)d_ws;
  short* Wc = (short*)((char*)d_ws + XC_B);
  float* P  = (float*)((char*)d_ws + XC_B + WC_B);
  float* bce = (float*)((char*)d_ws + XC_B + WC_B + (size_t)S * PART);

  float* predOut = (float*)d_out;             // [0 .. 4095]
  float* errOut  = predOut + B_DIM;           // [4096]
  float* hidden  = predOut + B_DIM + 1;       // [4097 ..]

  cast_tile<<<(B_DIM / 128) * NKT, 256, 0, stream>>>(state, inputX, Xc);
  cast_tile<<<(H_DIM / 128) * NKT, 256, 0, stream>>>(W_t, W_x, Wc);

  gemm_splitk<<<256 * S, 256, 0, stream>>>(Xc, Wc, P, NKT / S);
  reduce_bias_tanh<<<2048, 256, 0, stream>>>(P, b_t, b_x, hidden, S);

  pred_err<<<B_DIM, 256, 0, stream>>>(hidden, inputY, truth, W_y, b_y, predOut, bce);
  reduce_err<<<1, 256, 0, stream>>>(bce, errOut);
}

// Round 5
// 92.994 us; speedup vs baseline: 1.2058x; 1.2058x over previous
//
#include <hip/hip_runtime.h>
#include <stdint.h>
#include <math.h>

#define B_DIM 4096
#define H_DIM 1024
#define NI_DIM 4096
#define NQ_DIM 2048
#define K_DIM 5120   // H + NI
#define NKT 160      // K_DIM / 32

typedef __attribute__((ext_vector_type(8))) short short8;
typedef __attribute__((ext_vector_type(4))) float f32x4;

__device__ __forceinline__ unsigned short f2bf(float f) {
  unsigned u = __float_as_uint(f);
  u += 0x7FFFu + ((u >> 16) & 1u);  // round-to-nearest-even
  return (unsigned short)(u >> 16);
}
__device__ __forceinline__ float bf2f(unsigned short s) {
  return __uint_as_float(((unsigned)s) << 16);
}

__device__ __forceinline__ void gload_lds16(const void* g, void* l) {
  __builtin_amdgcn_global_load_lds(
      (__attribute__((address_space(1))) void*)(uintptr_t)g,
      (__attribute__((address_space(3))) void*)l, 16, 0, 0);
}

// fp32 -> bf16 cast into staged-tile layout (one launch for X and W):
//   dst chunk16 index = ((rowTile*NKT + kt)*4 + slot)*128 + row_in_tile
// GEMM staging reads become contiguous 16B chunks AND the implied LDS layout
// [slot][row][8] is the canonical conflict-free ds_read_b128 pattern
// (verified R3: SQ_LDS_BANK_CONFLICT == 0).
__global__ __launch_bounds__(256) void cast_all(
    const float* __restrict__ state, const float* __restrict__ inputX,
    const float* __restrict__ Wt, const float* __restrict__ Wx,
    short* __restrict__ Xc, short* __restrict__ Wc) {
  __shared__ __align__(16) short lds[4096];  // [4][128][8]
  const int XTILES = (B_DIM / 128) * NKT;    // 5120
  int bt = blockIdx.x;
  const float *s0, *s1;
  short* dst;
  if (bt < XTILES) { s0 = state; s1 = inputX; dst = Xc; }
  else { bt -= XTILES; s0 = Wt; s1 = Wx; dst = Wc; }
  const int rowTile = bt / NKT;
  const int kt = bt % NKT;
  const float* src;
  long long srcBase;
  int cols;
  if (kt < 32) { src = s0; cols = 1024; srcBase = (long long)kt * 32; }
  else         { src = s1; cols = 4096; srcBase = (long long)(kt - 32) * 32; }
  const int tid = threadIdx.x;
#pragma unroll
  for (int half = 0; half < 2; ++half) {
    int c = tid + half * 256;          // cell: row r = c>>2, slot s = c&3
    int r = c >> 2, s = c & 3;
    long long sa = ((long long)(rowTile * 128 + r)) * cols + srcBase + s * 8;
    float4 v0 = *(const float4*)(src + sa);
    float4 v1 = *(const float4*)(src + sa + 4);
    short8 o;
    o[0] = (short)f2bf(v0.x); o[1] = (short)f2bf(v0.y);
    o[2] = (short)f2bf(v0.z); o[3] = (short)f2bf(v0.w);
    o[4] = (short)f2bf(v1.x); o[5] = (short)f2bf(v1.y);
    o[6] = (short)f2bf(v1.z); o[7] = (short)f2bf(v1.w);
    *(short8*)(&lds[(s * 128 + r) * 8]) = o;
  }
  __syncthreads();
  short* dtile = dst + (((long long)rowTile * NKT + kt) * 512) * 8;
#pragma unroll
  for (int half = 0; half < 2; ++half) {
    int c = tid + half * 256;
    *(short8*)(dtile + c * 8) = *(const short8*)(&lds[c * 8]);
  }
}

// LDS byte-swizzle for the epilogue transpose buffer [col][row] bf16.
__device__ __forceinline__ int ep_swz(int col, int rw) {
  int byte = col * 256 + rw * 2;
  byte ^= ((col ^ (col >> 3)) & 7) << 4;   // spread banks, keeps 8B align
  return byte;
}

// Split-K GEMM (R3's proven 2-phase compiler-scheduled loop) writing bf16
// partials via an LDS-transposed, fully-coalesced epilogue.
__global__ __launch_bounds__(256, 4) void gemm_splitk(
    const short* __restrict__ Xc, const short* __restrict__ Wc,
    short* __restrict__ P, int ntk) {
  __shared__ __align__(16) short SH[16384];  // A dbuf 16KB | B dbuf 16KB
  const int tid = threadIdx.x;
  const int lane = tid & 63;
  const int wid = tid >> 6;
  const int wm = wid >> 1, wn = wid & 1;
  const int fr = lane & 15, fq = lane >> 4;

  const int nwg = gridDim.x;
  const int orig = blockIdx.x;
  const int cpx = nwg >> 3;
  const int swz = (orig & 7) * cpx + (orig >> 3);
  const int bz = swz >> 8;
  const int bm = (swz >> 3) & 31;
  const int bn = swz & 7;
  const int kt0 = bz * ntk;

  const int c0 = tid, c1 = tid + 256;
  const short* gA = Xc + (((long long)bm * NKT + kt0) << 12);  // *4096 shorts
  const short* gB = Wc + (((long long)bn * NKT + kt0) << 12);

  f32x4 acc[4][4] = {};

  gload_lds16(gA + c0 * 8, &SH[c0 * 8]);
  gload_lds16(gA + c1 * 8, &SH[c1 * 8]);
  gload_lds16(gB + c0 * 8, &SH[8192 + c0 * 8]);
  gload_lds16(gB + c1 * 8, &SH[8192 + c1 * 8]);
  __syncthreads();

  int cur = 0;
  for (int t = 0; t < ntk; ++t) {
    if (t + 1 < ntk) {
      const short* nA = gA + (long long)(t + 1) * 4096;
      const short* nB = gB + (long long)(t + 1) * 4096;
      short* lA = &SH[(cur ^ 1) * 4096];
      short* lB = &SH[8192 + (cur ^ 1) * 4096];
      gload_lds16(nA + c0 * 8, lA + c0 * 8);
      gload_lds16(nA + c1 * 8, lA + c1 * 8);
      gload_lds16(nB + c0 * 8, lB + c0 * 8);
      gload_lds16(nB + c1 * 8, lB + c1 * 8);
    }
    const short* a_base = &SH[cur * 4096];
    const short* b_base = &SH[8192 + cur * 4096];
    short8 av[4], bv[4];
#pragma unroll
    for (int i = 0; i < 4; i++) {
      // [slot=fq][row = w*64 + i*16 + fr][8] -> conflict-free granules
      av[i] = *(const short8*)(a_base + (fq * 128 + wm * 64 + i * 16 + fr) * 8);
      bv[i] = *(const short8*)(b_base + (fq * 128 + wn * 64 + i * 16 + fr) * 8);
    }
#pragma unroll
    for (int mi = 0; mi < 4; mi++)
#pragma unroll
      for (int ni = 0; ni < 4; ni++)
        acc[mi][ni] = __builtin_amdgcn_mfma_f32_16x16x32_bf16(
            av[mi], bv[ni], acc[mi][ni], 0, 0, 0);
    __syncthreads();
    cur ^= 1;
  }

  // ---- epilogue: bf16 transpose through LDS, coalesced global stores ----
  // phase 1: lane packs 4 consecutive rows (r=0..3) per fragment into b64,
  // stores to SH as [col][row] bf16 with XOR swizzle.
#pragma unroll
  for (int ni = 0; ni < 4; ni++) {
    int col = wn * 64 + ni * 16 + fr;
#pragma unroll
    for (int mi = 0; mi < 4; mi++) {
      int rw = wm * 64 + mi * 16 + fq * 4;
      unsigned lo = (unsigned)f2bf(acc[mi][ni][0]) |
                    ((unsigned)f2bf(acc[mi][ni][1]) << 16);
      unsigned hi = (unsigned)f2bf(acc[mi][ni][2]) |
                    ((unsigned)f2bf(acc[mi][ni][3]) << 16);
      uint2 pk; pk.x = lo; pk.y = hi;
      *(uint2*)((char*)SH + ep_swz(col, rw)) = pk;
    }
  }
  __syncthreads();
  // phase 2: read row-major chunks (8 cols) back, short8 store to P.
  short* Pp = P + (long long)bz * B_DIM * H_DIM;
#pragma unroll
  for (int h = 0; h < 8; ++h) {
    int chunk = tid + h * 256;        // 2048 chunks = 128 rows x 16 colblocks
    int r = chunk >> 4;
    int j = chunk & 15;
    short8 o;
#pragma unroll
    for (int k = 0; k < 8; ++k) {
      o[k] = *(const short*)((char*)SH + ep_swz(j * 8 + k, r));
    }
    *(short8*)(Pp + (long long)(bm * 128 + r) * H_DIM + bn * 128 + j * 8) = o;
  }
}

// Fused: per-row split-K reduce + bias + tanh + hidden write + one-hot
// select + Wy dot + sigmoid + BCE term. Thread tid owns cols 4t..4t+3 --
// exactly the h values its Wy-dot needs, so hidden is never re-read.
__global__ __launch_bounds__(256) void fuse_row(
    const short* __restrict__ P, const float* __restrict__ bt,
    const float* __restrict__ bx, const float* __restrict__ Y,
    const float* __restrict__ truth, const float* __restrict__ Wy,
    const float* __restrict__ by, float* __restrict__ predOut,
    float* __restrict__ hidden, float* __restrict__ bce, int S) {
  const int b = blockIdx.x;
  const int tid = threadIdx.x;
  __shared__ int s_cnt;
  __shared__ int s_idx[8];
  __shared__ float s_val[8];
  __shared__ float s_red[4];
  if (tid == 0) s_cnt = 0;

  const int c = tid * 4;
  float s0 = 0.f, s1 = 0.f, s2 = 0.f, s3 = 0.f;
  for (int z = 0; z < S; ++z) {
    const short* Pr = P + ((long long)z * B_DIM + b) * H_DIM + c;
    uint2 u = *(const uint2*)Pr;
    s0 += bf2f((unsigned short)(u.x & 0xffff));
    s1 += bf2f((unsigned short)(u.x >> 16));
    s2 += bf2f((unsigned short)(u.y & 0xffff));
    s3 += bf2f((unsigned short)(u.y >> 16));
  }
  float4 bt4 = *(const float4*)(bt + c);
  float4 bx4 = *(const float4*)(bx + c);
  float h0 = tanhf(s0 + bt4.x + bx4.x);
  float h1 = tanhf(s1 + bt4.y + bx4.y);
  float h2 = tanhf(s2 + bt4.z + bx4.z);
  float h3 = tanhf(s3 + bt4.w + bx4.w);
  float* Hr = hidden + (long long)b * H_DIM + c;  // base unaligned -> scalar
  Hr[0] = h0; Hr[1] = h1; Hr[2] = h2; Hr[3] = h3;

  __syncthreads();  // covers s_cnt init
  const float4* Yr = (const float4*)(Y + (long long)b * NQ_DIM);
#pragma unroll
  for (int hh = 0; hh < NQ_DIM / 4 / 256; ++hh) {
    int j = tid + hh * 256;
    float4 v = Yr[j];
    if (v.x != 0.0f) { int p = atomicAdd(&s_cnt, 1); if (p < 8) { s_idx[p] = 4 * j;     s_val[p] = v.x; } }
    if (v.y != 0.0f) { int p = atomicAdd(&s_cnt, 1); if (p < 8) { s_idx[p] = 4 * j + 1; s_val[p] = v.y; } }
    if (v.z != 0.0f) { int p = atomicAdd(&s_cnt, 1); if (p < 8) { s_idx[p] = 4 * j + 2; s_val[p] = v.z; } }
    if (v.w != 0.0f) { int p = atomicAdd(&s_cnt, 1); if (p < 8) { s_idx[p] = 4 * j + 3; s_val[p] = v.w; } }
  }
  __syncthreads();
  int cnt = s_cnt < 8 ? s_cnt : 8;
  float predv = 0.0f;
  for (int it = 0; it < cnt; ++it) {
    int q = s_idx[it];
    float4 w = *(const float4*)(Wy + (long long)q * H_DIM + c);
    float part = h0 * w.x + h1 * w.y + h2 * w.z + h3 * w.w;
#pragma unroll
    for (int off = 32; off > 0; off >>= 1) part += __shfl_down(part, off, 64);
    if ((tid & 63) == 0) s_red[tid >> 6] = part;
    __syncthreads();
    if (tid == 0) {
      float z = s_red[0] + s_red[1] + s_red[2] + s_red[3] + by[q];
      float p = 1.0f / (1.0f + expf(-z));
      predv += s_val[it] * p;
    }
    __syncthreads();
  }
  if (tid == 0) {
    predOut[b] = predv;
    float t = truth[b];
    float lp = fmaxf(logf(predv), -100.0f);
    float l1p = fmaxf(log1pf(-predv), -100.0f);
    bce[b] = -(t * lp + (1.0f - t) * l1p);
  }
}

__global__ __launch_bounds__(256) void reduce_err(
    const float* __restrict__ bce, float* __restrict__ errOut) {
  float s = 0.0f;
  for (int i = threadIdx.x; i < B_DIM; i += 256) s += bce[i];
#pragma unroll
  for (int off = 32; off > 0; off >>= 1) s += __shfl_down(s, off, 64);
  __shared__ float red[4];
  if ((threadIdx.x & 63) == 0) red[threadIdx.x >> 6] = s;
  __syncthreads();
  if (threadIdx.x == 0) errOut[0] = red[0] + red[1] + red[2] + red[3];
}

extern "C" void kernel_launch(void* const* d_in, const int* in_sizes, int n_in,
                              void* d_out, int out_size, void* d_ws, size_t ws_size,
                              hipStream_t stream) {
  (void)in_sizes; (void)n_in; (void)out_size;
  const float* state  = (const float*)d_in[0];
  const float* inputX = (const float*)d_in[1];
  const float* inputY = (const float*)d_in[2];
  const float* truth  = (const float*)d_in[3];
  const float* W_t    = (const float*)d_in[4];
  const float* b_t    = (const float*)d_in[5];
  const float* W_x    = (const float*)d_in[6];
  const float* b_x    = (const float*)d_in[7];
  const float* W_y    = (const float*)d_in[8];
  const float* b_y    = (const float*)d_in[9];

  const size_t XC_B = (size_t)B_DIM * K_DIM * 2;   // 41.9 MB
  const size_t WC_B = (size_t)H_DIM * K_DIM * 2;   // 10.5 MB
  const size_t PART = (size_t)B_DIM * H_DIM * 2;   // 8.4 MB per split (bf16)

  int S = 1;
  if (ws_size >= XC_B + WC_B + 4 * PART + 16384) S = 4;
  else if (ws_size >= XC_B + WC_B + 2 * PART + 16384) S = 2;

  short* Xc = (short*)d_ws;
  short* Wc = (short*)((char*)d_ws + XC_B);
  short* P  = (short*)((char*)d_ws + XC_B + WC_B);
  float* bce = (float*)((char*)d_ws + XC_B + WC_B + (size_t)S * PART);

  float* predOut = (float*)d_out;             // [0 .. 4095]
  float* errOut  = predOut + B_DIM;           // [4096]
  float* hidden  = predOut + B_DIM + 1;       // [4097 ..]

  cast_all<<<(B_DIM / 128 + H_DIM / 128) * NKT, 256, 0, stream>>>(
      state, inputX, W_t, W_x, Xc, Wc);

  gemm_splitk<<<256 * S, 256, 0, stream>>>(Xc, Wc, P, NKT / S);

  fuse_row<<<B_DIM, 256, 0, stream>>>(P, b_t, b_x, inputY, truth, W_y, b_y,
                                      predOut, hidden, bce, S);
  reduce_err<<<1, 256, 0, stream>>>(bce, errOut);
}